// Round 1
// baseline (943.111 us; speedup 1.0000x reference)
//
#include <hip/hip_runtime.h>
#include <math.h>

#define HH 384
#define WW 384
#define BB 8
#define CIN 32
#define CMID 16
#define COUT 32
#define HWP (HH*WW)   // 147456

// ws layout (float offsets):
//   gap:    0 .. 255          [b][cin]
//   f5:     256 .. 383        [b][c]
//   B1b:    384 .. 511        [b][c]  (sum_i sw_i*b_i + sw4*f5)
//   nfs:    512 .. 1023       [b][i<4][c]  (zeroed by memset, atomicAdd)
//   W2:     1024 .. 5119      [b][c][co]
//   wT:     5120 .. 19455     [cin][pos28][c]  transposed branch weights
//   S:      32768 .. +18874368
#define WS_GAP 0
#define WS_F5 256
#define WS_B1B 384
#define WS_NFS 512
#define WS_W2 1024
#define WS_WT 5120
#define WS_S 32768

// ---------------- gap: per-(b,cin) spatial mean of x ----------------
__global__ void gap_kernel(const float* __restrict__ x, float* __restrict__ gap) {
    int plane = blockIdx.x;  // b*32+cin, 256 planes
    const float4* xp = (const float4*)(x + (size_t)plane * HWP);
    float s = 0.f;
    for (int i = threadIdx.x; i < HWP/4; i += 1024) {
        float4 v = xp[i];
        s += (v.x + v.y) + (v.z + v.w);
    }
    __shared__ float red[16];
    #pragma unroll
    for (int o = 32; o; o >>= 1) s += __shfl_down(s, o);
    if ((threadIdx.x & 63) == 0) red[threadIdx.x >> 6] = s;
    __syncthreads();
    if (threadIdx.x < 16) {
        float t = red[threadIdx.x];
        #pragma unroll
        for (int o = 8; o; o >>= 1) t += __shfl_down(t, o);
        if (threadIdx.x == 0) gap[plane] = t * (1.f / (float)HWP);
    }
}

__device__ __forceinline__ void softmax5(const float* attn, float sw[5]) {
    float a0=attn[0],a1=attn[1],a2=attn[2],a3=attn[3],a4=attn[4];
    float m = fmaxf(fmaxf(fmaxf(a0,a1),fmaxf(a2,a3)),a4);
    float e0=expf(a0-m),e1=expf(a1-m),e2=expf(a2-m),e3=expf(a3-m),e4=expf(a4-m);
    float inv = 1.f/(e0+e1+e2+e3+e4);
    sw[0]=e0*inv; sw[1]=e1*inv; sw[2]=e2*inv; sw[3]=e3*inv; sw[4]=e4*inv;
}

// ---------------- prep1: f5, folded bias, transposed weights ----------------
__global__ void prep1_kernel(const float* __restrict__ w1, const float* __restrict__ b1,
                             const float* __restrict__ w2, const float* __restrict__ b2,
                             const float* __restrict__ w3, const float* __restrict__ b3,
                             const float* __restrict__ w4, const float* __restrict__ b4,
                             const float* __restrict__ w5, const float* __restrict__ b5,
                             const float* __restrict__ attn, float* __restrict__ ws) {
    float* gap = ws + WS_GAP;
    float* f5  = ws + WS_F5;
    float* B1b = ws + WS_B1B;
    float* wT  = ws + WS_WT;
    float sw[5];
    softmax5(attn, sw);
    int t = threadIdx.x;
    if (t < 128) {
        int b = t >> 4, c = t & 15;
        float acc = b5[c];
        for (int ci = 0; ci < CIN; ++ci) acc += w5[c*CIN+ci] * gap[b*CIN+ci];
        f5[t] = acc;
        B1b[t] = sw[0]*b1[c] + sw[1]*b2[c] + sw[2]*b3[c] + sw[3]*b4[c] + sw[4]*acc;
    }
    // wT[cin][pos][c]: pos 0 = w1 (1x1); 1..9 = w2 taps; 10..18 = w3; 19..27 = w4
    for (int idx = t; idx < CIN*28*CMID; idx += blockDim.x) {
        int c = idx & 15; int r = idx >> 4; int pos = r % 28; int cin = r / 28;
        float v;
        if (pos == 0)       v = w1[c*CIN + cin];
        else if (pos < 10)  v = w2[c*288 + cin*9 + (pos-1)];
        else if (pos < 19)  v = w3[c*288 + cin*9 + (pos-10)];
        else                v = w4[c*288 + cin*9 + (pos-19)];
        wT[idx] = v;
    }
}

// ---------------- conv: the hot kernel ----------------
// 16x16 spatial tile per block, all 16 mid channels, 4 branches separately.
// x staged into LDS in cin-chunks of 8 with +/-3 halo (22x22).
__global__ __launch_bounds__(256) void conv_kernel(
        const float* __restrict__ x, const float* __restrict__ attn,
        const float* __restrict__ ws_ro, float* __restrict__ S, float* __restrict__ nfs) {
    __shared__ float lds[8*22*22];   // 3872 floats
    __shared__ float rbuf[4*64];
    int blk = blockIdx.x;
    int b = blk / 576; int t = blk % 576;
    int h0 = (t / 24) * 16, w0 = (t % 24) * 16;
    int tid = threadIdx.x; int ty = tid >> 4, tx = tid & 15;
    float sw[5];
    softmax5(attn, sw);
    const float* wT  = ws_ro + WS_WT;
    const float* B1b = ws_ro + WS_B1B;

    float fc1[16], fc2[16], fc3[16], fc4[16];
    #pragma unroll
    for (int c = 0; c < 16; ++c) { fc1[c]=0.f; fc2[c]=0.f; fc3[c]=0.f; fc4[c]=0.f; }

    for (int cb = 0; cb < CIN; cb += 8) {
        // stage x chunk
        for (int i = tid; i < 3872; i += 256) {
            int ci = i / 484, r2 = i % 484;
            int r = r2 / 22, cc = r2 % 22;
            int gh = h0 - 3 + r, gw = w0 - 3 + cc;
            float v = 0.f;
            if ((unsigned)gh < (unsigned)HH && (unsigned)gw < (unsigned)WW)
                v = x[(size_t)(b*CIN + cb + ci) * HWP + gh*WW + gw];
            lds[i] = v;
        }
        __syncthreads();
        for (int ci = 0; ci < 8; ++ci) {
            const float* lp = lds + ci*484 + ty*22 + tx;
            const float* wt = wT + (cb + ci)*448;   // uniform -> s_load
            float xc = lp[3*22 + 3];
            #pragma unroll
            for (int c = 0; c < 16; ++c) fc1[c] = fmaf(wt[c], xc, fc1[c]);
            // branch 2: dilation 1
            #pragma unroll
            for (int kh = 0; kh < 3; ++kh)
            #pragma unroll
            for (int kw = 0; kw < 3; ++kw) {
                float xv = lp[(3 + (kh-1))*22 + 3 + (kw-1)];
                const float* wp = wt + (1 + kh*3 + kw)*16;
                #pragma unroll
                for (int c = 0; c < 16; ++c) fc2[c] = fmaf(wp[c], xv, fc2[c]);
            }
            // branch 3: dilation 2
            #pragma unroll
            for (int kh = 0; kh < 3; ++kh)
            #pragma unroll
            for (int kw = 0; kw < 3; ++kw) {
                float xv = lp[(3 + (kh-1)*2)*22 + 3 + (kw-1)*2];
                const float* wp = wt + (10 + kh*3 + kw)*16;
                #pragma unroll
                for (int c = 0; c < 16; ++c) fc3[c] = fmaf(wp[c], xv, fc3[c]);
            }
            // branch 4: dilation 3
            #pragma unroll
            for (int kh = 0; kh < 3; ++kh)
            #pragma unroll
            for (int kw = 0; kw < 3; ++kw) {
                float xv = lp[(3 + (kh-1)*3)*22 + 3 + (kw-1)*3];
                const float* wp = wt + (19 + kh*3 + kw)*16;
                #pragma unroll
                for (int c = 0; c < 16; ++c) fc4[c] = fmaf(wp[c], xv, fc4[c]);
            }
        }
        __syncthreads();
    }

    // exact per-branch spatial sums -> node_feats means
    int wv = tid >> 6, ln = tid & 63;
    {
        #pragma unroll
        for (int c = 0; c < 16; ++c) {
            float v = fc1[c];
            #pragma unroll
            for (int o = 32; o; o >>= 1) v += __shfl_down(v, o);
            if (ln == 0) rbuf[wv*64 + 0*16 + c] = v;
        }
        #pragma unroll
        for (int c = 0; c < 16; ++c) {
            float v = fc2[c];
            #pragma unroll
            for (int o = 32; o; o >>= 1) v += __shfl_down(v, o);
            if (ln == 0) rbuf[wv*64 + 1*16 + c] = v;
        }
        #pragma unroll
        for (int c = 0; c < 16; ++c) {
            float v = fc3[c];
            #pragma unroll
            for (int o = 32; o; o >>= 1) v += __shfl_down(v, o);
            if (ln == 0) rbuf[wv*64 + 2*16 + c] = v;
        }
        #pragma unroll
        for (int c = 0; c < 16; ++c) {
            float v = fc4[c];
            #pragma unroll
            for (int o = 32; o; o >>= 1) v += __shfl_down(v, o);
            if (ln == 0) rbuf[wv*64 + 3*16 + c] = v;
        }
    }
    __syncthreads();
    if (tid < 64) {
        float v = rbuf[tid] + rbuf[64+tid] + rbuf[128+tid] + rbuf[192+tid];
        atomicAdd(&nfs[b*64 + tid], v);
    }

    // S = sum_i sw_i * f_i  (biases folded: B1b includes sw4*f5 broadcast)
    int p = (h0 + ty)*WW + (w0 + tx);
    #pragma unroll
    for (int c = 0; c < 16; ++c) {
        float s = sw[0]*fc1[c] + sw[1]*fc2[c] + sw[2]*fc3[c] + sw[3]*fc4[c] + B1b[b*16+c];
        S[(size_t)(b*16 + c) * HWP + p] = s;
    }
}

// ---------------- prep2: node feats -> GCN -> g -> W2 ----------------
__global__ void prep2_kernel(const float* __restrict__ b1, const float* __restrict__ b2,
                             const float* __restrict__ b3, const float* __restrict__ b4,
                             const float* __restrict__ gcn_w, const float* __restrict__ gcn_b,
                             const float* __restrict__ fusion_w, float* __restrict__ ws) {
    const float* f5  = ws + WS_F5;
    const float* nfs = ws + WS_NFS;
    float* W2 = ws + WS_W2;
    __shared__ float nsum[128];
    __shared__ float g[128];
    int t = threadIdx.x;
    if (t < 128) {
        int b = t >> 4, c = t & 15;
        const float inv = 1.f / (float)HWP;
        float s = (nfs[b*64 + 0*16 + c]*inv + b1[c])
                + (nfs[b*64 + 1*16 + c]*inv + b2[c])
                + (nfs[b*64 + 2*16 + c]*inv + b3[c])
                + (nfs[b*64 + 3*16 + c]*inv + b4[c])
                + f5[b*16 + c];
        nsum[t] = 0.2f * s;
    }
    __syncthreads();
    if (t < 128) {
        int b = t >> 4, c = t & 15;
        float acc = gcn_b[c];
        for (int k = 0; k < 16; ++k) acc += nsum[b*16 + k] * gcn_w[k*16 + c];
        g[t] = acc;
    }
    __syncthreads();
    for (int idx = t; idx < 4096; idx += blockDim.x) {
        int co = idx & 31; int r = idx >> 5;   // r = b*16+c
        W2[idx] = fusion_w[co*16 + (r & 15)] * g[r];
    }
}

// ---------------- fuse: final 1x1 conv, 16 -> 32 channels ----------------
__global__ __launch_bounds__(256) void fuse_kernel(const float* __restrict__ ws_ro,
                                                   const float* __restrict__ fusion_b,
                                                   float* __restrict__ out) {
    const float* S  = ws_ro + WS_S;
    const float* W2 = ws_ro + WS_W2;
    int blk = blockIdx.x;          // 4608
    int b = blk / 576;
    int p = (blk % 576) * 256 + threadIdx.x;
    float acc[32];
    #pragma unroll
    for (int co = 0; co < 32; ++co) acc[co] = fusion_b[co];
    #pragma unroll
    for (int c = 0; c < 16; ++c) {
        float sv = S[(size_t)(b*16 + c) * HWP + p];
        const float* w = W2 + (b*16 + c)*32;   // uniform -> s_load
        #pragma unroll
        for (int co = 0; co < 32; ++co) acc[co] = fmaf(w[co], sv, acc[co]);
    }
    #pragma unroll
    for (int co = 0; co < 32; ++co) out[(size_t)(b*32 + co) * HWP + p] = acc[co];
}

extern "C" void kernel_launch(void* const* d_in, const int* in_sizes, int n_in,
                              void* d_out, int out_size, void* d_ws, size_t ws_size,
                              hipStream_t stream) {
    const float* x     = (const float*)d_in[0];
    const float* w1    = (const float*)d_in[1];  const float* b1 = (const float*)d_in[2];
    const float* w2    = (const float*)d_in[3];  const float* b2 = (const float*)d_in[4];
    const float* w3    = (const float*)d_in[5];  const float* b3 = (const float*)d_in[6];
    const float* w4    = (const float*)d_in[7];  const float* b4 = (const float*)d_in[8];
    const float* w5    = (const float*)d_in[9];  const float* b5 = (const float*)d_in[10];
    const float* gcn_w = (const float*)d_in[11]; const float* gcn_b = (const float*)d_in[12];
    const float* attn  = (const float*)d_in[13];
    const float* fw    = (const float*)d_in[14]; const float* fb = (const float*)d_in[15];
    float* ws  = (float*)d_ws;
    float* out = (float*)d_out;

    // zero the node-feature accumulators (ws is poisoned before every call)
    hipMemsetAsync(ws + WS_NFS, 0, 512 * sizeof(float), stream);

    gap_kernel  <<<256, 1024, 0, stream>>>(x, ws + WS_GAP);
    prep1_kernel<<<1, 256, 0, stream>>>(w1,b1,w2,b2,w3,b3,w4,b4,w5,b5,attn,ws);
    conv_kernel <<<4608, 256, 0, stream>>>(x, attn, ws, ws + WS_S, ws + WS_NFS);
    prep2_kernel<<<1, 256, 0, stream>>>(b1,b2,b3,b4,gcn_w,gcn_b,fw,ws);
    fuse_kernel <<<4608, 256, 0, stream>>>(ws, fb, out);
}

// Round 2
// 485.075 us; speedup vs baseline: 1.9443x; 1.9443x over previous
//
#include <hip/hip_runtime.h>
#include <math.h>

#define HH 384
#define WW 384
#define BB 8
#define CIN 32
#define CMID 16
#define COUT 32
#define HWP (HH*WW)   // 147456

// ws layout (float offsets):
#define WS_GAP  0        // [b][cin] 256
#define WS_BORD 256      // [plane][48] strip/corner sums, 12288
#define WS_F5   12544    // [b][c] 128
#define WS_CB   12672    // fuse const [b][co] 256
#define WS_W2   12928    // [b][c][co] 4096
#define WS_WBF  17024    // 25 taps x 64 lanes x 8 bf16 = 12800 ushort = 6400 floats
#define WS_S    32768    // S pixel-major [b][p][c] fp32: 8*147456*16

typedef __attribute__((ext_vector_type(8))) __bf16 bf16x8;
typedef __attribute__((ext_vector_type(4))) float  f32x4;

__device__ __forceinline__ unsigned bf16r(float f) {   // RNE fp32->bf16 bits
    unsigned u = __float_as_uint(f);
    return (u + 0x7fffu + ((u >> 16) & 1u)) >> 16;
}

__device__ __forceinline__ void softmax5(const float* attn, float sw[5]) {
    float a0=attn[0],a1=attn[1],a2=attn[2],a3=attn[3],a4=attn[4];
    float m = fmaxf(fmaxf(fmaxf(a0,a1),fmaxf(a2,a3)),a4);
    float e0=expf(a0-m),e1=expf(a1-m),e2=expf(a2-m),e3=expf(a3-m),e4=expf(a4-m);
    float inv = 1.f/(e0+e1+e2+e3+e4);
    sw[0]=e0*inv; sw[1]=e1*inv; sw[2]=e2*inv; sw[3]=e3*inv; sw[4]=e4*inv;
}

// ---------------- gap: per-(b,cin) spatial mean of x ----------------
__global__ void gap_kernel(const float* __restrict__ x, float* __restrict__ gap) {
    int plane = blockIdx.x;  // 256 planes
    const float4* xp = (const float4*)(x + (size_t)plane * HWP);
    float s = 0.f;
    for (int i = threadIdx.x; i < HWP/4; i += 1024) {
        float4 v = xp[i];
        s += (v.x + v.y) + (v.z + v.w);
    }
    __shared__ float red[16];
    #pragma unroll
    for (int o = 32; o; o >>= 1) s += __shfl_down(s, o);
    if ((threadIdx.x & 63) == 0) red[threadIdx.x >> 6] = s;
    __syncthreads();
    if (threadIdx.x < 16) {
        float t = red[threadIdx.x];
        #pragma unroll
        for (int o = 8; o; o >>= 1) t += __shfl_down(t, o);
        if (threadIdx.x == 0) gap[plane] = t * (1.f / (float)HWP);
    }
}

// ---------------- border: strip + corner sums per plane ----------------
__device__ __forceinline__ float blockReduce256(float v, float* red) {
    #pragma unroll
    for (int o = 32; o; o >>= 1) v += __shfl_down(v, o);
    if ((threadIdx.x & 63) == 0) red[threadIdx.x >> 6] = v;
    __syncthreads();
    float r = 0.f;
    if (threadIdx.x == 0) r = red[0] + red[1] + red[2] + red[3];
    __syncthreads();
    return r;   // valid on thread 0 only
}

__global__ void border_kernel(const float* __restrict__ x, float* __restrict__ bord) {
    int plane = blockIdx.x;
    const float* xp = x + (size_t)plane * HWP;
    __shared__ float red[4];
    __shared__ float rs[6], cs[6];
    int t = threadIdx.x;   // 256
    for (int j = 0; j < 6; ++j) {
        int r = (j < 3) ? j : 378 + j;   // 0,1,2,381,382,383
        float s = 0.f;
        for (int i = t; i < WW; i += 256) s += xp[r*WW + i];
        s = blockReduce256(s, red);
        if (t == 0) rs[j] = s;
    }
    for (int j = 0; j < 6; ++j) {
        int c = (j < 3) ? j : 378 + j;
        float s = 0.f;
        for (int i = t; i < HH; i += 256) s += xp[i*WW + c];
        s = blockReduce256(s, red);
        if (t == 0) cs[j] = s;
    }
    __syncthreads();
    if (t == 0) {
        float* bd = bord + plane*48;
        bd[0]=rs[0]; bd[1]=rs[0]+rs[1]; bd[2]=rs[0]+rs[1]+rs[2];
        bd[3]=rs[5]; bd[4]=rs[5]+rs[4]; bd[5]=rs[5]+rs[4]+rs[3];
        bd[6]=cs[0]; bd[7]=cs[0]+cs[1]; bd[8]=cs[0]+cs[1]+cs[2];
        bd[9]=cs[5]; bd[10]=cs[5]+cs[4]; bd[11]=cs[5]+cs[4]+cs[3];
        for (int a = 1; a <= 3; ++a)
        for (int b2 = 1; b2 <= 3; ++b2) {
            float tl=0,tr=0,bl=0,br=0;
            for (int h = 0; h < a; ++h)
            for (int w = 0; w < b2; ++w) {
                tl += xp[h*WW + w];
                tr += xp[h*WW + (WW-1-w)];
                bl += xp[(HH-1-h)*WW + w];
                br += xp[(HH-1-h)*WW + (WW-1-w)];
            }
            int o = (a-1)*3 + (b2-1);
            bd[12+o]=tl; bd[21+o]=tr; bd[30+o]=bl; bd[39+o]=br;
        }
    }
}

// ---------------- prep1: f5 + fragment-ordered merged tap weights ----------------
__global__ void prep1_kernel(const float* __restrict__ w1, const float* __restrict__ w2,
                             const float* __restrict__ w3, const float* __restrict__ w4,
                             const float* __restrict__ w5, const float* __restrict__ b5,
                             const float* __restrict__ attn, float* __restrict__ ws) {
    const float* gap = ws + WS_GAP;
    float* f5 = ws + WS_F5;
    unsigned short* wbf = (unsigned short*)(ws + WS_WBF);
    float sw[5];
    softmax5(attn, sw);
    int t = threadIdx.x;
    if (t < 128) {
        int b = t >> 4, c = t & 15;
        float acc = b5[c];
        for (int ci = 0; ci < CIN; ++ci) acc += w5[c*CIN+ci] * gap[b*CIN+ci];
        f5[t] = acc;
    }
    // wBf[tap][lane][j] = bf16( Wc[tap][cin=(lane>>4)*8+j][c=lane&15] )
    const int tk[8] = {0,1,2,3,5,6,7,8};
    for (int idx = t; idx < 25*512; idx += blockDim.x) {
        int tap  = idx >> 9;
        int lane = (idx >> 3) & 63;
        int j    = idx & 7;
        int cin  = ((lane >> 4) << 3) | j;
        int c    = lane & 15;
        float v;
        if (tap == 0) {
            v = sw[0]*w1[c*CIN+cin]
              + sw[1]*w2[c*288 + cin*9 + 4]
              + sw[2]*w3[c*288 + cin*9 + 4]
              + sw[3]*w4[c*288 + cin*9 + 4];
        } else {
            int g = (tap-1) >> 3;          // 0,1,2 -> branch 2,3,4
            int m = (tap-1) & 7;
            int kk = tk[m];
            const float* w = (g == 0) ? w2 : ((g == 1) ? w3 : w4);
            v = sw[g+1] * w[c*288 + cin*9 + kk];
        }
        wbf[idx] = (unsigned short)bf16r(v);
    }
}

// ---------------- conv: MFMA implicit-GEMM, 25 merged taps, K=32 ----------------
__global__ __launch_bounds__(256) void conv_kernel(
        const float* __restrict__ x, const unsigned short* __restrict__ wBf,
        float* __restrict__ S) {
    __shared__ __align__(16) unsigned short sx[484*40];   // [haloPix][cin pad40] bf16
    int blk = blockIdx.x;
    int b = blk / 576; int tno = blk % 576;
    int h0 = (tno / 24) * 16, w0 = (tno % 24) * 16;
    int tid = threadIdx.x;

    // ---- stage: fp32 [cin][h][w] -> bf16 LDS [pix][cin] ----
    int i0 = tid, i1 = tid + 256;
    int r0i = i0 / 22, c0i = i0 - r0i*22;
    int r1i = i1 / 22, c1i = i1 - r1i*22;
    int gh0 = h0 - 3 + r0i, gw0 = w0 - 3 + c0i;
    int gh1 = h0 - 3 + r1i, gw1 = w0 - 3 + c1i;
    bool ok0 = ((unsigned)gh0 < (unsigned)HH) && ((unsigned)gw0 < (unsigned)WW);
    bool ok1 = ((unsigned)gh1 < (unsigned)HH) && ((unsigned)gw1 < (unsigned)WW) && (i1 < 484);
    bool has1 = (i1 < 484);
    int go0 = ok0 ? (gh0*WW + gw0) : 0;
    int go1 = ok1 ? (gh1*WW + gw1) : 0;
    unsigned* sxu = (unsigned*)sx;
    const float* xb = x + (size_t)b * CIN * HWP;
    #pragma unroll 4
    for (int cp = 0; cp < 16; ++cp) {
        const float* p0 = xb + (size_t)(2*cp) * HWP;
        const float* p1 = p0 + HWP;
        float a0 = ok0 ? p0[go0] : 0.f;
        float a1 = ok0 ? p1[go0] : 0.f;
        sxu[i0*20 + cp] = bf16r(a0) | (bf16r(a1) << 16);
        if (has1) {
            float d0 = ok1 ? p0[go1] : 0.f;
            float d1 = ok1 ? p1[go1] : 0.f;
            sxu[i1*20 + cp] = bf16r(d0) | (bf16r(d1) << 16);
        }
    }
    __syncthreads();

    // ---- compute: per wave 4 pixel-rows x 25 taps ----
    int lane = tid & 63, wv = tid >> 6;
    int m = lane & 15, q = lane >> 4;
    int by0 = ((wv*4 + 0 + 3)*22 + 3 + m)*40 + q*8;
    int by1 = by0 + 22*40;
    int by2 = by1 + 22*40;
    int by3 = by2 + 22*40;
    const unsigned short* wfp = wBf + lane*8;

    f32x4 acc0 = {0.f,0.f,0.f,0.f}, acc1 = {0.f,0.f,0.f,0.f};
    f32x4 acc2 = {0.f,0.f,0.f,0.f}, acc3 = {0.f,0.f,0.f,0.f};

    constexpr int TDH[25] = {0, -1,-1,-1,0,0,1,1,1, -2,-2,-2,0,0,2,2,2, -3,-3,-3,0,0,3,3,3};
    constexpr int TDW[25] = {0, -1,0,1,-1,1,-1,0,1, -2,0,2,-2,2,-2,0,2, -3,0,3,-3,3,-3,0,3};
    #pragma unroll
    for (int tap = 0; tap < 25; ++tap) {
        bf16x8 bw = *(const bf16x8*)(wfp + tap*512);
        const int to = (TDH[tap]*22 + TDW[tap])*40;
        acc0 = __builtin_amdgcn_mfma_f32_16x16x32_bf16(*(const bf16x8*)(sx + by0 + to), bw, acc0, 0, 0, 0);
        acc1 = __builtin_amdgcn_mfma_f32_16x16x32_bf16(*(const bf16x8*)(sx + by1 + to), bw, acc1, 0, 0, 0);
        acc2 = __builtin_amdgcn_mfma_f32_16x16x32_bf16(*(const bf16x8*)(sx + by2 + to), bw, acc2, 0, 0, 0);
        acc3 = __builtin_amdgcn_mfma_f32_16x16x32_bf16(*(const bf16x8*)(sx + by3 + to), bw, acc3, 0, 0, 0);
    }

    // ---- store S pixel-major: lane holds c = lane&15, pixel col = q*4+r ----
    #pragma unroll
    for (int g2 = 0; g2 < 4; ++g2) {
        int y = wv*4 + g2;
        float* sp = S + ((size_t)b*HWP + (size_t)(h0 + y)*WW + w0) * 16;
        f32x4 a = (g2 == 0) ? acc0 : (g2 == 1) ? acc1 : (g2 == 2) ? acc2 : acc3;
        #pragma unroll
        for (int r = 0; r < 4; ++r) {
            int px = q*4 + r;
            sp[px*16 + m] = a[r];
        }
    }
}

// ---------------- prep2: exact node feats -> GCN -> W2 + fuse const ----------------
__device__ __forceinline__ float rectsum(const float* bd, float T, int dh, int dw) {
    int r0 = dh > 0 ?  dh : 0, b0 = dh < 0 ? -dh : 0;
    int c0 = dw > 0 ?  dw : 0, d0 = dw < 0 ? -dw : 0;
    float v = T;
    if (r0) v -= bd[r0-1];
    if (b0) v -= bd[3+b0-1];
    if (c0) v -= bd[6+c0-1];
    if (d0) v -= bd[9+d0-1];
    if (r0 && c0) v += bd[12+(r0-1)*3+(c0-1)];
    if (r0 && d0) v += bd[21+(r0-1)*3+(d0-1)];
    if (b0 && c0) v += bd[30+(b0-1)*3+(c0-1)];
    if (b0 && d0) v += bd[39+(b0-1)*3+(d0-1)];
    return v;
}

__global__ void prep2_kernel(const float* __restrict__ w1,
                             const float* __restrict__ b1, const float* __restrict__ w2,
                             const float* __restrict__ b2, const float* __restrict__ w3,
                             const float* __restrict__ b3, const float* __restrict__ w4,
                             const float* __restrict__ b4,
                             const float* __restrict__ gcn_w, const float* __restrict__ gcn_b,
                             const float* __restrict__ fusion_w, const float* __restrict__ fusion_b,
                             const float* __restrict__ attn, float* __restrict__ ws) {
    const float* gap  = ws + WS_GAP;
    const float* bord = ws + WS_BORD;
    const float* f5   = ws + WS_F5;
    float* W2 = ws + WS_W2;
    float* CB = ws + WS_CB;
    __shared__ float ns[128];    // nsum
    __shared__ float bbf[128];   // B1b
    __shared__ float gl[128];    // g
    float sw[5];
    softmax5(attn, sw);
    int t = threadIdx.x;
    const float invHW = 1.f / (float)HWP;
    if (t < 128) {
        int b = t >> 4, c = t & 15;
        float nf1 = b1[c];
        float s2 = 0.f, s3 = 0.f, s4 = 0.f;
        for (int cin = 0; cin < CIN; ++cin) {
            nf1 += w1[c*CIN+cin] * gap[b*CIN+cin];
            const float* bd = bord + (b*CIN + cin)*48;
            float T = gap[b*CIN+cin] * (float)HWP;
            #pragma unroll
            for (int kk = 0; kk < 9; ++kk) {
                int dh = (kk/3) - 1, dw = (kk%3) - 1;
                float wv2 = w2[c*288 + cin*9 + kk];
                float wv3 = w3[c*288 + cin*9 + kk];
                float wv4 = w4[c*288 + cin*9 + kk];
                s2 += wv2 * rectsum(bd, T, dh,   dw);
                s3 += wv3 * rectsum(bd, T, 2*dh, 2*dw);
                s4 += wv4 * rectsum(bd, T, 3*dh, 3*dw);
            }
        }
        float nf2 = b2[c] + s2*invHW;
        float nf3 = b3[c] + s3*invHW;
        float nf4 = b4[c] + s4*invHW;
        float nf5 = f5[b*16 + c];
        ns[t]  = 0.2f * (nf1 + nf2 + nf3 + nf4 + nf5);
        bbf[t] = sw[0]*b1[c] + sw[1]*b2[c] + sw[2]*b3[c] + sw[3]*b4[c] + sw[4]*nf5;
    }
    __syncthreads();
    if (t < 128) {
        int b = t >> 4, c = t & 15;
        float acc = gcn_b[c];
        for (int k = 0; k < 16; ++k) acc += ns[b*16 + k] * gcn_w[k*16 + c];
        gl[t] = acc;
    }
    __syncthreads();
    for (int idx = t; idx < 4096; idx += blockDim.x) {
        int b = idx >> 9, c = (idx >> 5) & 15, co = idx & 31;
        W2[idx] = fusion_w[co*16 + c] * gl[b*16 + c];
    }
    if (t < 256) {
        int b = t >> 5, co = t & 31;
        float acc = fusion_b[co];
        for (int c = 0; c < 16; ++c)
            acc += fusion_w[co*16 + c] * gl[b*16 + c] * bbf[b*16 + c];
        CB[t] = acc;
    }
}

// ---------------- fuse: out[b,co,p] = sum_c W2[b,c,co]*S[b,p,c] + CB[b,co] ----------------
__global__ __launch_bounds__(256) void fuse_kernel(const float* __restrict__ ws_ro,
                                                   float* __restrict__ out) {
    __shared__ float w2s[512];
    __shared__ float cbs[32];
    int blk = blockIdx.x;            // 4608
    int b = blk / 576;
    int pl = (blk % 576) * 256 + threadIdx.x;
    int t = threadIdx.x;
    const float* W2 = ws_ro + WS_W2 + b*512;
    w2s[t] = W2[t];
    w2s[t + 256] = W2[t + 256];
    if (t < 32) cbs[t] = ws_ro[WS_CB + b*32 + t];
    __syncthreads();

    const float4* sp = (const float4*)(ws_ro + WS_S + ((size_t)b*HWP + pl)*16);
    float4 s0 = sp[0], s1 = sp[1], s2 = sp[2], s3 = sp[3];
    float sv[16] = {s0.x,s0.y,s0.z,s0.w, s1.x,s1.y,s1.z,s1.w,
                    s2.x,s2.y,s2.z,s2.w, s3.x,s3.y,s3.z,s3.w};
    float acc[32];
    #pragma unroll
    for (int co = 0; co < 32; ++co) acc[co] = cbs[co];
    #pragma unroll
    for (int c = 0; c < 16; ++c) {
        float v = sv[c];
        #pragma unroll
        for (int co = 0; co < 32; ++co) acc[co] = fmaf(w2s[c*32 + co], v, acc[co]);
    }
    float* ob = out + (size_t)b * COUT * HWP + pl;
    #pragma unroll
    for (int co = 0; co < 32; ++co) ob[(size_t)co * HWP] = acc[co];
}

extern "C" void kernel_launch(void* const* d_in, const int* in_sizes, int n_in,
                              void* d_out, int out_size, void* d_ws, size_t ws_size,
                              hipStream_t stream) {
    const float* x     = (const float*)d_in[0];
    const float* w1    = (const float*)d_in[1];  const float* b1 = (const float*)d_in[2];
    const float* w2    = (const float*)d_in[3];  const float* b2 = (const float*)d_in[4];
    const float* w3    = (const float*)d_in[5];  const float* b3 = (const float*)d_in[6];
    const float* w4    = (const float*)d_in[7];  const float* b4 = (const float*)d_in[8];
    const float* w5    = (const float*)d_in[9];  const float* b5 = (const float*)d_in[10];
    const float* gcn_w = (const float*)d_in[11]; const float* gcn_b = (const float*)d_in[12];
    const float* attn  = (const float*)d_in[13];
    const float* fw    = (const float*)d_in[14]; const float* fb = (const float*)d_in[15];
    float* ws  = (float*)d_ws;
    float* out = (float*)d_out;

    gap_kernel   <<<256, 1024, 0, stream>>>(x, ws + WS_GAP);
    border_kernel<<<256, 256, 0, stream>>>(x, ws + WS_BORD);
    prep1_kernel <<<1, 256, 0, stream>>>(w1, w2, w3, w4, w5, b5, attn, ws);
    conv_kernel  <<<4608, 256, 0, stream>>>(x, (const unsigned short*)(ws + WS_WBF), ws + WS_S);
    prep2_kernel <<<1, 256, 0, stream>>>(w1, b1, w2, b2, w3, b3, w4, b4,
                                         gcn_w, gcn_b, fw, fb, attn, ws);
    fuse_kernel  <<<4608, 256, 0, stream>>>(ws, out);
}

// Round 3
// 481.271 us; speedup vs baseline: 1.9596x; 1.0079x over previous
//
#include <hip/hip_runtime.h>
#include <math.h>

#define HH 384
#define WW 384
#define CIN 32
#define HWP (HH*WW)   // 147456

// ws float offsets
#define WS_GSUM 0      // [plane] 256  (atomic, memset 0)
#define WS_ROWS 256    // [plane][6] raw row sums (rows 0,1,2,381,382,383)
#define WS_COLS 1792   // [plane][6] col strip sums (atomic, memset 0)
#define WS_W2   3328   // [b][c][co] 4096
#define WS_CB   7424   // [b][co] 256
#define WS_WBF  7680   // 25*512 ushort = 6400 floats
#define WS_XBF  16384  // bf16 x pixel-major: 8*147456*32 ushort

typedef __attribute__((ext_vector_type(8))) __bf16 bf16x8;
typedef __attribute__((ext_vector_type(4))) float  f32x4;

__device__ __forceinline__ unsigned bf16r(float f) {   // RNE fp32->bf16 bits
    unsigned u = __float_as_uint(f);
    return (u + 0x7fffu + ((u >> 16) & 1u)) >> 16;
}

__device__ __forceinline__ void softmax5(const float* attn, float sw[5]) {
    float a0=attn[0],a1=attn[1],a2=attn[2],a3=attn[3],a4=attn[4];
    float m = fmaxf(fmaxf(fmaxf(a0,a1),fmaxf(a2,a3)),a4);
    float e0=expf(a0-m),e1=expf(a1-m),e2=expf(a2-m),e3=expf(a3-m),e4=expf(a4-m);
    float inv = 1.f/(e0+e1+e2+e3+e4);
    sw[0]=e0*inv; sw[1]=e1*inv; sw[2]=e2*inv; sw[3]=e3*inv; sw[4]=e4*inv;
}

// ---------------- transform: NCHW fp32 -> pixel-major bf16 + gap + border strips ----------------
__global__ __launch_bounds__(384) void transform_kernel(const float* __restrict__ x,
        float* __restrict__ ws, unsigned short* __restrict__ xbf) {
    int b = blockIdx.x / HH, h = blockIdx.x % HH;
    int t = threadIdx.x;   // = w
    const float* xp = x + (size_t)b*CIN*HWP + (size_t)h*WW + t;
    float v[32];
    #pragma unroll
    for (int ci = 0; ci < 32; ++ci) v[ci] = xp[(size_t)ci*HWP];

    // bf16 pixel-major store: 64 B contiguous per pixel
    unsigned uu[16];
    #pragma unroll
    for (int k = 0; k < 16; ++k) uu[k] = bf16r(v[2*k]) | (bf16r(v[2*k+1]) << 16);
    uint4* dst = (uint4*)(xbf + ((size_t)b*HWP + (size_t)h*WW + t)*32);
    dst[0] = make_uint4(uu[0],uu[1],uu[2],uu[3]);
    dst[1] = make_uint4(uu[4],uu[5],uu[6],uu[7]);
    dst[2] = make_uint4(uu[8],uu[9],uu[10],uu[11]);
    dst[3] = make_uint4(uu[12],uu[13],uu[14],uu[15]);

    // col strip contributions (cols 0,1,2 -> j 0,1,2; 381,382,383 -> 3,4,5)
    int cj = (t < 3) ? t : ((t >= 381) ? t - 378 : -1);
    if (cj >= 0) {
        #pragma unroll
        for (int ci = 0; ci < 32; ++ci)
            atomicAdd(&ws[WS_COLS + (b*32 + ci)*6 + cj], v[ci]);
    }

    // per-plane row sums -> gap atomics (+ row strips)
    __shared__ float red[32][6];
    int wv = t >> 6, ln = t & 63;
    #pragma unroll
    for (int ci = 0; ci < 32; ++ci) {
        float s = v[ci];
        #pragma unroll
        for (int o = 32; o; o >>= 1) s += __shfl_down(s, o);
        if (ln == 0) red[ci][wv] = s;
    }
    __syncthreads();
    if (t < 32) {
        float rsum = red[t][0]+red[t][1]+red[t][2]+red[t][3]+red[t][4]+red[t][5];
        atomicAdd(&ws[WS_GSUM + b*32 + t], rsum);
        int rj = (h < 3) ? h : ((h >= 381) ? h - 378 : -1);
        if (rj >= 0) ws[WS_ROWS + (b*32 + t)*6 + rj] = rsum;
    }
}

// ---------------- prep: corners, f5, taps, node feats, GCN, W2, CB ----------------
__device__ __forceinline__ float rectsum(const float* bd, float T, int dh, int dw) {
    int r0 = dh > 0 ?  dh : 0, b0 = dh < 0 ? -dh : 0;
    int c0 = dw > 0 ?  dw : 0, d0 = dw < 0 ? -dw : 0;
    float v = T;
    if (r0) v -= bd[r0-1];
    if (b0) v -= bd[3+b0-1];
    if (c0) v -= bd[6+c0-1];
    if (d0) v -= bd[9+d0-1];
    if (r0 && c0) v += bd[12+(r0-1)*3+(c0-1)];
    if (r0 && d0) v += bd[21+(r0-1)*3+(d0-1)];
    if (b0 && c0) v += bd[30+(b0-1)*3+(c0-1)];
    if (b0 && d0) v += bd[39+(b0-1)*3+(d0-1)];
    return v;
}

__global__ void prep_kernel(const float* __restrict__ x,
                            const float* __restrict__ w1, const float* __restrict__ b1,
                            const float* __restrict__ w2, const float* __restrict__ b2,
                            const float* __restrict__ w3, const float* __restrict__ b3,
                            const float* __restrict__ w4, const float* __restrict__ b4,
                            const float* __restrict__ w5, const float* __restrict__ b5,
                            const float* __restrict__ gcn_w, const float* __restrict__ gcn_b,
                            const float* __restrict__ fusion_w, const float* __restrict__ fusion_b,
                            const float* __restrict__ attn, float* __restrict__ ws) {
    __shared__ float sbd[256*48];
    __shared__ float ns[128], bbf[128], gl[128];
    float sw[5];
    softmax5(attn, sw);
    int t = threadIdx.x;   // 256
    const float invHW = 1.f / (float)HWP;

    // A: per-plane bd table (strip cums from ws + fresh corner prefixes from x)
    {
        int plane = t;
        float* bd = sbd + plane*48;
        const float* rw = ws + WS_ROWS + plane*6;
        const float* cl = ws + WS_COLS + plane*6;
        bd[0]=rw[0]; bd[1]=rw[0]+rw[1]; bd[2]=rw[0]+rw[1]+rw[2];
        bd[3]=rw[5]; bd[4]=rw[5]+rw[4]; bd[5]=rw[5]+rw[4]+rw[3];
        bd[6]=cl[0]; bd[7]=cl[0]+cl[1]; bd[8]=cl[0]+cl[1]+cl[2];
        bd[9]=cl[5]; bd[10]=cl[5]+cl[4]; bd[11]=cl[5]+cl[4]+cl[3];
        const float* xp = x + (size_t)plane*HWP;
        for (int a = 1; a <= 3; ++a)
        for (int b2 = 1; b2 <= 3; ++b2) {
            float tl=0,tr=0,bl=0,br=0;
            for (int h = 0; h < a; ++h)
            for (int w = 0; w < b2; ++w) {
                tl += xp[h*WW + w];
                tr += xp[h*WW + (WW-1-w)];
                bl += xp[(HH-1-h)*WW + w];
                br += xp[(HH-1-h)*WW + (WW-1-w)];
            }
            int o = (a-1)*3 + (b2-1);
            bd[12+o]=tl; bd[21+o]=tr; bd[30+o]=bl; bd[39+o]=br;
        }
    }

    // B: f5 (kept in register) + bf16 merged taps
    float f5v = 0.f;
    if (t < 128) {
        int b = t >> 4, c = t & 15;
        f5v = b5[c];
        for (int ci = 0; ci < CIN; ++ci)
            f5v += w5[c*CIN+ci] * ws[WS_GSUM + b*32 + ci] * invHW;
    }
    {
        unsigned short* wbf = (unsigned short*)(ws + WS_WBF);
        const int tk[8] = {0,1,2,3,5,6,7,8};
        for (int idx = t; idx < 25*512; idx += blockDim.x) {
            int tap  = idx >> 9;
            int lane = (idx >> 3) & 63;
            int j    = idx & 7;
            int cin  = ((lane >> 4) << 3) | j;
            int c    = lane & 15;
            float v;
            if (tap == 0) {
                v = sw[0]*w1[c*CIN+cin]
                  + sw[1]*w2[c*288 + cin*9 + 4]
                  + sw[2]*w3[c*288 + cin*9 + 4]
                  + sw[3]*w4[c*288 + cin*9 + 4];
            } else {
                int g = (tap-1) >> 3;
                int mth = (tap-1) & 7;
                int kk = tk[mth];
                const float* w = (g == 0) ? w2 : ((g == 1) ? w3 : w4);
                v = sw[g+1] * w[c*288 + cin*9 + kk];
            }
            wbf[idx] = (unsigned short)bf16r(v);
        }
    }
    __syncthreads();

    // C: exact node feats
    if (t < 128) {
        int b = t >> 4, c = t & 15;
        float nf1 = b1[c];
        float s2 = 0.f, s3 = 0.f, s4 = 0.f;
        for (int cin = 0; cin < CIN; ++cin) {
            int plane = b*32 + cin;
            float T = ws[WS_GSUM + plane];
            nf1 += w1[c*CIN+cin] * T * invHW;
            const float* bd = sbd + plane*48;
            #pragma unroll
            for (int kk = 0; kk < 9; ++kk) {
                int dh = (kk/3) - 1, dw = (kk%3) - 1;
                s2 += w2[c*288 + cin*9 + kk] * rectsum(bd, T, dh,   dw);
                s3 += w3[c*288 + cin*9 + kk] * rectsum(bd, T, 2*dh, 2*dw);
                s4 += w4[c*288 + cin*9 + kk] * rectsum(bd, T, 3*dh, 3*dw);
            }
        }
        float nf2 = b2[c] + s2*invHW;
        float nf3 = b3[c] + s3*invHW;
        float nf4 = b4[c] + s4*invHW;
        ns[t]  = 0.2f * (nf1 + nf2 + nf3 + nf4 + f5v);
        bbf[t] = sw[0]*b1[c] + sw[1]*b2[c] + sw[2]*b3[c] + sw[3]*b4[c] + sw[4]*f5v;
    }
    __syncthreads();
    if (t < 128) {
        int b = t >> 4, c = t & 15;
        float acc = gcn_b[c];
        for (int k = 0; k < 16; ++k) acc += ns[b*16 + k] * gcn_w[k*16 + c];
        gl[t] = acc;
    }
    __syncthreads();
    for (int idx = t; idx < 4096; idx += blockDim.x) {
        int b = idx >> 9, c = (idx >> 5) & 15, co = idx & 31;
        ws[WS_W2 + idx] = fusion_w[co*16 + c] * gl[b*16 + c];
    }
    {
        int b = t >> 5, co = t & 31;
        float acc = fusion_b[co];
        for (int c = 0; c < 16; ++c)
            acc += fusion_w[co*16 + c] * gl[b*16 + c] * bbf[b*16 + c];
        ws[WS_CB + t] = acc;
    }
}

// ---------------- convfuse: MFMA conv + fused 16->32 mix, writes out directly ----------------
__global__ __launch_bounds__(256) void convfuse_kernel(
        const unsigned short* __restrict__ xbf, const unsigned short* __restrict__ wBf,
        const float* __restrict__ ws_ro, float* __restrict__ out) {
    __shared__ __align__(16) char smem[40896];
    unsigned short* sx = (unsigned short*)smem;        // [484 pix][40 bf16]
    float* w2s = (float*)(smem + 38720);               // 512 f
    float* cbs = (float*)(smem + 40768);               // 32 f
    int blk = blockIdx.x;
    int b = blk / 576, tno = blk % 576;
    int h0 = (tno / 24) * 16, w0 = (tno % 24) * 16;
    int tid = threadIdx.x;

    w2s[tid]       = ws_ro[WS_W2 + b*512 + tid];
    w2s[tid + 256] = ws_ro[WS_W2 + b*512 + 256 + tid];
    if (tid < 32) cbs[tid] = ws_ro[WS_CB + b*32 + tid];

    // stage bf16 halo pixels (64 B contiguous each)
    for (int p = tid; p < 484; p += 256) {
        int r = p / 22, c = p - r*22;
        int gh = h0 - 3 + r, gw = w0 - 3 + c;
        uint4 a0 = {0,0,0,0}, a1 = a0, a2 = a0, a3 = a0;
        if ((unsigned)gh < (unsigned)HH && (unsigned)gw < (unsigned)WW) {
            const uint4* src = (const uint4*)(xbf + ((size_t)b*HWP + (size_t)gh*WW + gw)*32);
            a0 = src[0]; a1 = src[1]; a2 = src[2]; a3 = src[3];
        }
        uint4* d = (uint4*)(sx + p*40);
        d[0] = a0; d[1] = a1; d[2] = a2; d[3] = a3;
    }
    __syncthreads();

    int lane = tid & 63, wv = tid >> 6;
    int m = lane & 15, q = lane >> 4;
    int by0 = ((wv*4 + 0 + 3)*22 + 3 + m)*40 + q*8;
    int by1 = by0 + 22*40;
    int by2 = by1 + 22*40;
    int by3 = by2 + 22*40;
    const unsigned short* wfp = wBf + lane*8;

    f32x4 acc0 = {0.f,0.f,0.f,0.f}, acc1 = {0.f,0.f,0.f,0.f};
    f32x4 acc2 = {0.f,0.f,0.f,0.f}, acc3 = {0.f,0.f,0.f,0.f};

    constexpr int TDH[25] = {0, -1,-1,-1,0,0,1,1,1, -2,-2,-2,0,0,2,2,2, -3,-3,-3,0,0,3,3,3};
    constexpr int TDW[25] = {0, -1,0,1,-1,1,-1,0,1, -2,0,2,-2,2,-2,0,2, -3,0,3,-3,3,-3,0,3};
    #pragma unroll
    for (int tap = 0; tap < 25; ++tap) {
        bf16x8 bw = *(const bf16x8*)(wfp + tap*512);
        const int to = (TDH[tap]*22 + TDW[tap])*40;
        acc0 = __builtin_amdgcn_mfma_f32_16x16x32_bf16(*(const bf16x8*)(sx + by0 + to), bw, acc0, 0, 0, 0);
        acc1 = __builtin_amdgcn_mfma_f32_16x16x32_bf16(*(const bf16x8*)(sx + by1 + to), bw, acc1, 0, 0, 0);
        acc2 = __builtin_amdgcn_mfma_f32_16x16x32_bf16(*(const bf16x8*)(sx + by2 + to), bw, acc2, 0, 0, 0);
        acc3 = __builtin_amdgcn_mfma_f32_16x16x32_bf16(*(const bf16x8*)(sx + by3 + to), bw, acc3, 0, 0, 0);
    }
    __syncthreads();   // done reading sx; reuse as fp32 S-tile

    // transpose acc through LDS: st[pix(256)][c] stride 17
    float* st = (float*)smem;
    #pragma unroll
    for (int g2 = 0; g2 < 4; ++g2) {
        int y = wv*4 + g2;
        f32x4 a = (g2 == 0) ? acc0 : (g2 == 1) ? acc1 : (g2 == 2) ? acc2 : acc3;
        #pragma unroll
        for (int r = 0; r < 4; ++r) {
            int px = q*4 + r;
            st[(y*16 + px)*17 + m] = a[r];
        }
    }
    __syncthreads();

    // per-thread pixel: 16 -> 32 mix + store
    float sv[16];
    #pragma unroll
    for (int c = 0; c < 16; ++c) sv[c] = st[tid*17 + c];
    float acc[32];
    #pragma unroll
    for (int co = 0; co < 32; ++co) acc[co] = cbs[co];
    #pragma unroll
    for (int c = 0; c < 16; ++c) {
        float v = sv[c];
        #pragma unroll
        for (int co = 0; co < 32; ++co) acc[co] = fmaf(w2s[c*32 + co], v, acc[co]);
    }
    int y = tid >> 4, px = tid & 15;
    float* ob = out + (size_t)b*32*HWP + (size_t)(h0 + y)*WW + w0 + px;
    #pragma unroll
    for (int co = 0; co < 32; ++co) ob[(size_t)co * HWP] = acc[co];
}

extern "C" void kernel_launch(void* const* d_in, const int* in_sizes, int n_in,
                              void* d_out, int out_size, void* d_ws, size_t ws_size,
                              hipStream_t stream) {
    const float* x     = (const float*)d_in[0];
    const float* w1    = (const float*)d_in[1];  const float* b1 = (const float*)d_in[2];
    const float* w2    = (const float*)d_in[3];  const float* b2 = (const float*)d_in[4];
    const float* w3    = (const float*)d_in[5];  const float* b3 = (const float*)d_in[6];
    const float* w4    = (const float*)d_in[7];  const float* b4 = (const float*)d_in[8];
    const float* w5    = (const float*)d_in[9];  const float* b5 = (const float*)d_in[10];
    const float* gcn_w = (const float*)d_in[11]; const float* gcn_b = (const float*)d_in[12];
    const float* attn  = (const float*)d_in[13];
    const float* fw    = (const float*)d_in[14]; const float* fb = (const float*)d_in[15];
    float* ws  = (float*)d_ws;
    float* out = (float*)d_out;
    unsigned short* xbf = (unsigned short*)(ws + WS_XBF);

    hipMemsetAsync(ws, 0, 3328 * sizeof(float), stream);   // gsum + rows + cols
    transform_kernel<<<8*HH, 384, 0, stream>>>(x, ws, xbf);
    prep_kernel     <<<1, 256, 0, stream>>>(x, w1,b1,w2,b2,w3,b3,w4,b4,w5,b5,
                                            gcn_w, gcn_b, fw, fb, attn, ws);
    convfuse_kernel <<<4608, 256, 0, stream>>>(xbf, (const unsigned short*)(ws + WS_WBF), ws, out);
}